// Round 3
// baseline (784.340 us; speedup 1.0000x reference)
//
#include <hip/hip_runtime.h>

// Fused attention, Q=K=V=X: out = softmax(X X^T / sqrt(512)) X
// B=4, N=4096, D=512, fp32 in/out, bf16 MFMA compute.
//
// Round-3: 512-thread blocks (8 waves, launch_bounds(512,2) -> 2 waves/SIMD
// for latency hiding). Wave w: q-set wset=w&3 (16 rows), key-half kh=w>>2.
// QK: each wave computes S[16q x 16keys] on its half-tile. P is BLOCK-SHARED
// [64][40] in LDS; PV splits dims across waves (64 dims each) so V B-frags
// are reused across all 4 q-sets (PV LDS reads /4). Row-sum l via one MFMA
// with a ones B-operand, reusing PV's P A-fragment.
// Conflict-free swizzles (per-phase bank analysis):
//   Xrow[key][512]: block' = dg ^ (key&7) ^ ((key>>3)<<1)   (key bits -> banks)
//   Xcol 4 planes [kb][512 d][8 keys], dg-rotated b64 write order, plain reads
// Double-buffered tiles: 2x64 KB + P 5 KB + l 256 B = 136.4 KB LDS.

#define Nq 4096
#define Dm 512
#define SCALE 0.044194173824159216f  // 1/sqrt(512)
#define MOFF 24.0f                   // fixed softmax offset (max score ~29)

typedef __attribute__((ext_vector_type(8))) short short8;
typedef __attribute__((ext_vector_type(4))) float floatx4;

union U16x8 { short8 v; uint w[4]; };

__device__ __forceinline__ uint pack_bf16(float a, float b) {
  // round-half-up bf16(a) in low 16, bf16(b) in high 16
  uint ua = __float_as_uint(a) + 0x8000u;
  uint ub = __float_as_uint(b) + 0x8000u;
  return (ua >> 16) | (ub & 0xFFFF0000u);
}

__global__ __launch_bounds__(512, 2) void attn_fused(
    const float* __restrict__ X, float* __restrict__ Out) {
  // ushort units: buf k at k*32768 (Xrow 16384 | Xcol 16384)
  // P at 65536: [64][40]; l_sh at 68096 (64 floats)
  __shared__ ushort SH[68224];  // 136448 B
  ushort* const Psh = SH + 65536;
  float* const l_sh = (float*)(SH + 68096);

  const int tid  = threadIdx.x;
  const int w    = tid >> 6;
  const int lane = tid & 63;
  const int quad = lane >> 4;
  const int l15  = lane & 15;
  const int wset = w & 3;       // q-set (16 rows)
  const int kh   = w >> 2;      // key half of each 32-key tile
  const int b    = blockIdx.x & 3;
  const int qt   = blockIdx.x >> 2;
  const int q0   = qt * 64;
  const float* Xb = X + (size_t)b * Nq * Dm;

  // staging role: wave-uniform (kb=8-key plane, h=4-key nibble), lane = dg
  const int kb = wset;          // plane 0..3 (keys kb*8 .. kb*8+8)
  const int h  = kh;            // nibble: keys kb*8 + h*4 + j, j=0..3
  const int dg = lane;          // dim group (8 dims), 0..63 -> coalesced loads

  auto load_tile = [&](int k0, float4* lv) {
    const float* src = Xb + (size_t)(k0 + kb * 8 + h * 4) * Dm + dg * 8;
    #pragma unroll
    for (int j = 0; j < 4; ++j) {
      lv[2 * j]     = *(const float4*)(src + (size_t)j * Dm);
      lv[2 * j + 1] = *(const float4*)(src + (size_t)j * Dm + 4);
    }
  };
  auto write_tile = [&](const float4* lv, int buf) {
    ushort* const xrow = SH + buf * 32768;
    ushort* const xcol = xrow + 16384;
    uint kw[4][4];  // kw[j][p] = bf16 dims (2p,2p+1) of key kb*8+h*4+j
    #pragma unroll
    for (int j = 0; j < 4; ++j) {
      kw[j][0] = pack_bf16(lv[2 * j].x, lv[2 * j].y);
      kw[j][1] = pack_bf16(lv[2 * j].z, lv[2 * j].w);
      kw[j][2] = pack_bf16(lv[2 * j + 1].x, lv[2 * j + 1].y);
      kw[j][3] = pack_bf16(lv[2 * j + 1].z, lv[2 * j + 1].w);
    }
    // Xrow: 4 x b128; swizzle makes (key&7, key>>3) reach the bank index
    #pragma unroll
    for (int j = 0; j < 4; ++j) {
      const int key = kb * 8 + h * 4 + j;
      const int swz = (key & 7) ^ ((key >> 3) << 1);
      U16x8 t;
      t.w[0] = kw[j][0]; t.w[1] = kw[j][1]; t.w[2] = kw[j][2]; t.w[3] = kw[j][3];
      *(short8*)(xrow + key * 512 + ((dg ^ swz) * 8)) = t.v;
    }
    // Xcol planes: [kb][d][8 keys]; dg-rotated write order -> distinct banks
    #pragma unroll
    for (int i = 0; i < 8; ++i) {
      const int ii = (i + dg) & 7;       // local dim index this instr
      const int d  = dg * 8 + ii;
      const int p  = ii >> 1;
      uint2 u;
      if (ii & 1) {
        u.x = (kw[0][p] >> 16) | (kw[1][p] & 0xFFFF0000u);
        u.y = (kw[2][p] >> 16) | (kw[3][p] & 0xFFFF0000u);
      } else {
        u.x = (kw[0][p] & 0xFFFFu) | (kw[1][p] << 16);
        u.y = (kw[2][p] & 0xFFFFu) | (kw[3][p] << 16);
      }
      *(uint2*)(xcol + kb * 4096 + d * 8 + h * 4) = u;
    }
  };

  // ---- Q fragments (A-layout: A[m=l15][k=quad*8+j]), scale folded in ----
  short8 qf[16];
  {
    const float* qrow = Xb + (size_t)(q0 + wset * 16 + l15) * Dm + quad * 8;
    #pragma unroll
    for (int kk = 0; kk < 16; ++kk) {
      float4 a = *(const float4*)(qrow + kk * 32);
      float4 c = *(const float4*)(qrow + kk * 32 + 4);
      U16x8 t;
      t.w[0] = pack_bf16(a.x * SCALE, a.y * SCALE);
      t.w[1] = pack_bf16(a.z * SCALE, a.w * SCALE);
      t.w[2] = pack_bf16(c.x * SCALE, c.y * SCALE);
      t.w[3] = pack_bf16(c.z * SCALE, c.w * SCALE);
      qf[kk] = t.v;
    }
  }

  floatx4 o[4][4];  // o[qset][ngroup]: O[64 q][w*64 + n*16 + l15]
  #pragma unroll
  for (int s = 0; s < 4; ++s)
    #pragma unroll
    for (int n = 0; n < 4; ++n) o[s][n] = (floatx4){0.f, 0.f, 0.f, 0.f};
  floatx4 l_acc = (floatx4){0.f, 0.f, 0.f, 0.f};
  short8 onesf;
  { U16x8 t; t.w[0] = t.w[1] = t.w[2] = t.w[3] = 0x3F803F80u; onesf = t.v; }

  // ---- prologue: stage tile 0 into buf 0 ----
  {
    float4 lv[8];
    load_tile(0, lv);
    write_tile(lv, 0);
  }
  __syncthreads();

  const int key0 = kh * 16;
  const int keyr = key0 + l15;                       // this lane's QK key
  const int swzr = (keyr & 7) ^ ((keyr >> 3) << 1);  // matches write swizzle

  for (int kt = 0; kt < 128; ++kt) {
    const int cur = kt & 1;
    const ushort* const xrow_r = SH + cur * 32768;
    const ushort* const xcol_r = xrow_r + 16384;

    // issue next tile's global loads now; consumed at the tail
    float4 lv[8];
    load_tile(((kt + 1) & 127) * 32, lv);

    // ---- QK^T: S[16 q][16 keys] (this wave's key half) ----
    floatx4 s = {0.f, 0.f, 0.f, 0.f};
    const ushort* const krow = xrow_r + keyr * 512;
    #pragma unroll
    for (int kk = 0; kk < 16; ++kk) {
      short8 kf = *(const short8*)(krow + (((kk * 4 + quad) ^ swzr) * 8));
      s = __builtin_amdgcn_mfma_f32_16x16x32_bf16(qf[kk], kf, s, 0, 0, 0);
    }

    // ---- fixed-offset softmax -> shared P ----
    #pragma unroll
    for (int r = 0; r < 4; ++r) {
      float p = __expf(s[r] - MOFF);
      Psh[(wset * 16 + quad * 4 + r) * 40 + key0 + l15] =
          (ushort)((__float_as_uint(p) + 0x8000u) >> 16);
    }
    __syncthreads();  // barrier 1: P complete (all waves)

    // ---- PV: O[64 q][64 dims of wave] ; V frags reused across 4 q-sets ----
    short8 vf[4];
    #pragma unroll
    for (int n = 0; n < 4; ++n)
      vf[n] = *(const short8*)(xcol_r + quad * 4096 + (w * 64 + n * 16 + l15) * 8);
    #pragma unroll
    for (int sQ = 0; sQ < 4; ++sQ) {
      short8 pf = *(const short8*)(Psh + (sQ * 16 + l15) * 40 + quad * 8);
      if (sQ == wset)  // wave-uniform
        l_acc = __builtin_amdgcn_mfma_f32_16x16x32_bf16(pf, onesf, l_acc, 0, 0, 0);
      #pragma unroll
      for (int n = 0; n < 4; ++n)
        o[sQ][n] = __builtin_amdgcn_mfma_f32_16x16x32_bf16(pf, vf[n], o[sQ][n], 0, 0, 0);
    }

    // ---- stage next tile into the other buffer ----
    write_tile(lv, (kt + 1) & 1);
    __syncthreads();  // barrier 2: staged; P/Xcol reads done before reuse
  }

  // ---- share l across waves (per-row sums; identical in wave pairs) ----
  if (kh == 0 && l15 == 0) {
    #pragma unroll
    for (int r = 0; r < 4; ++r) l_sh[wset * 16 + quad * 4 + r] = l_acc[r];
  }
  __syncthreads();

  // ---- epilogue: O / l, write fp32 ----
  #pragma unroll
  for (int sQ = 0; sQ < 4; ++sQ) {
    float linv[4];
    #pragma unroll
    for (int r = 0; r < 4; ++r)
      linv[r] = __builtin_amdgcn_rcpf(l_sh[sQ * 16 + quad * 4 + r]);
    #pragma unroll
    for (int n = 0; n < 4; ++n) {
      float* obase = Out + (size_t)b * Nq * Dm +
                     (size_t)(q0 + sQ * 16 + quad * 4) * Dm + w * 64 + n * 16 + l15;
      #pragma unroll
      for (int r = 0; r < 4; ++r)
        obase[(size_t)r * Dm] = o[sQ][n][r] * linv[r];
    }
  }
}

extern "C" void kernel_launch(void* const* d_in, const int* in_sizes, int n_in,
                              void* d_out, int out_size, void* d_ws, size_t ws_size,
                              hipStream_t stream) {
  const float* X = (const float*)d_in[0];
  float* Out = (float*)d_out;
  attn_fused<<<dim3(256), dim3(512), 0, stream>>>(X, Out);
}

// Round 6
// 660.972 us; speedup vs baseline: 1.1866x; 1.1866x over previous
//
#include <hip/hip_runtime.h>

// Fused attention, Q=K=V=X: out = softmax(X X^T / sqrt(512)) X
// B=4, N=4096, D=512, fp32 in/out, bf16 MFMA compute.
//
// Round-6: bisect r5's failure. Keep the prepack kernel (tile image verified
// by element-level derivation = r3's passing layout) but replace the
// global_load_lds DMA (unverifiable M0/dest semantics; prime suspect) with
// plain register staging: thread t copies 16 B at linear offset j*8192+t*16
// from G (coalesced uint4, issued at loop top -> hidden under QK) and
// ds_write_b128 to the same linear LDS offset at the tail (conflict-free).
// Compute structure = round 3 (passed): 8 waves, wave w: q-set w&3, key-half
// w>>2; block-shared P[64][40]; PV splits dims (V frags reused by 4 q-sets);
// row-sum l via MFMA with ones-operand. Fixed-offset softmax exp(s-24).

#define Nq 4096
#define Dm 512
#define SCALE 0.044194173824159216f  // 1/sqrt(512)
#define MOFF 24.0f                   // fixed softmax offset (max score ~29)

typedef __attribute__((ext_vector_type(8))) short short8;
typedef __attribute__((ext_vector_type(4))) float floatx4;

union U16x8 { short8 v; uint w[4]; };
union U16x8b { uint4 v; ushort u[8]; };

__device__ __forceinline__ uint pack_bf16(float a, float b) {
  // round-half-up bf16(a) in low 16, bf16(b) in high 16
  uint ua = __float_as_uint(a) + 0x8000u;
  uint ub = __float_as_uint(b) + 0x8000u;
  return (ua >> 16) | (ub & 0xFFFF0000u);
}

__device__ __forceinline__ int swzf(int key) {
  return (key & 7) ^ ((key >> 3) << 1);  // row-image block swizzle
}

// ---- prepack: X fp32 -> G[b][kt][64 KB tile image] (bf16) ------------------
// image ushort layout: [0,16384): row half  R[key*512 + jj*8 + e] =
//   X[key][(jj^swzf(key))*8+e];  [16384,32768): col half C[kb*4096 + d*8 + t]
//   = X[kb*8+t][d]
__global__ __launch_bounds__(256) void prepack(const float* __restrict__ X,
                                               ushort* __restrict__ G) {
  __shared__ __attribute__((aligned(16))) ushort R[16384];
  __shared__ __attribute__((aligned(16))) ushort C[16384];
  const int t  = threadIdx.x;
  const int b  = blockIdx.x >> 7;
  const int kt = blockIdx.x & 127;
  const float* src = X + ((size_t)b * Nq + kt * 32) * Dm;

  // phase 1: fp32 -> swizzled bf16 row-image in R (coalesced float4 loads)
  #pragma unroll
  for (int i = 0; i < 16; ++i) {
    int f = i * 256 + t;           // float4 index within the 32x512 tile
    int row = f >> 7, c = f & 127;
    float4 v = *(const float4*)(src + (size_t)row * Dm + c * 4);
    uint2 u;
    u.x = pack_bf16(v.x, v.y);
    u.y = pack_bf16(v.z, v.w);
    int jj = (c >> 1) ^ swzf(row);
    *(uint2*)(R + row * 512 + jj * 8 + (c & 1) * 4) = u;
  }
  __syncthreads();

  ushort* Gt = G + ((size_t)(b * 128 + kt) << 15);  // 32768 ush per tile
  // phase 2: R -> G row half (linear, coalesced)
  #pragma unroll
  for (int i = 0; i < 8; ++i) {
    int u = i * 256 + t;
    ((uint4*)Gt)[u] = ((const uint4*)R)[u];
  }
  // phase 3: build col-image in C (8x8 u16 register transpose per thread)
  {
    const int kb = t >> 6, dc = t & 63;
    U16x8b r[8];
    #pragma unroll
    for (int tt = 0; tt < 8; ++tt) {
      int key = kb * 8 + tt;
      r[tt].v = *(const uint4*)(R + key * 512 + (dc ^ swzf(key)) * 8);
    }
    #pragma unroll
    for (int i = 0; i < 8; ++i) {
      U16x8b o;
      #pragma unroll
      for (int tt = 0; tt < 8; ++tt) o.u[tt] = r[tt].u[i];
      *(uint4*)(C + kb * 4096 + (dc * 8 + i) * 8) = o.v;
    }
  }
  __syncthreads();
  // phase 4: C -> G col half (linear, coalesced)
  #pragma unroll
  for (int i = 0; i < 8; ++i) {
    int u = i * 256 + t;
    ((uint4*)(Gt + 16384))[u] = ((const uint4*)C)[u];
  }
}

// ---- fused attention kernel ------------------------------------------------
template <bool PRE>
__global__ __launch_bounds__(512) void attn_fused(
    const float* __restrict__ X, const ushort* __restrict__ G,
    float* __restrict__ Out) {
  // ushort units: buf k at k*32768 (row 16384 | col 16384)
  // P at 65536: [64][40]; l_sh at 68096 (64 floats)
  __shared__ __attribute__((aligned(16))) ushort SH[68224];  // 136448 B
  ushort* const Psh = SH + 65536;
  float* const l_sh = (float*)(SH + 68096);

  const int tid  = threadIdx.x;
  const int w    = tid >> 6;
  const int lane = tid & 63;
  const int quad = lane >> 4;
  const int l15  = lane & 15;
  const int wset = w & 3;       // q-set (16 rows)
  const int kh   = w >> 2;      // key half of each 32-key tile
  const int b    = blockIdx.x & 3;
  const int qt   = blockIdx.x >> 2;
  const int q0   = qt * 64;
  const float* Xb = X + (size_t)b * Nq * Dm;
  const ushort* Gb = PRE ? (G + ((size_t)b << 22)) : (const ushort*)nullptr;

  // PRE staging: thread t owns 8 x 16B at linear offsets j*8192 + t*16
  auto load_img = [&](int kt_next, uint4* lv) {
    const uint4* Gt4 = (const uint4*)(Gb + ((size_t)kt_next << 15));
    #pragma unroll
    for (int j = 0; j < 8; ++j) lv[j] = Gt4[j * 512 + tid];
  };
  auto write_img = [&](const uint4* lv, int buf) {
    uint4* dst4 = (uint4*)(SH + buf * 32768);
    #pragma unroll
    for (int j = 0; j < 8; ++j) dst4[j * 512 + tid] = lv[j];
  };

  // fallback staging (no workspace): round-3 verified pack path
  const int kb = wset, h = kh, dg = lane;
  auto load_tile = [&](int k0, float4* lv) {
    const float* s = Xb + (size_t)(k0 + kb * 8 + h * 4) * Dm + dg * 8;
    #pragma unroll
    for (int j = 0; j < 4; ++j) {
      lv[2 * j]     = *(const float4*)(s + (size_t)j * Dm);
      lv[2 * j + 1] = *(const float4*)(s + (size_t)j * Dm + 4);
    }
  };
  auto write_tile = [&](const float4* lv, int buf) {
    ushort* const xrow = SH + buf * 32768;
    ushort* const xcol = xrow + 16384;
    uint kw[4][4];
    #pragma unroll
    for (int j = 0; j < 4; ++j) {
      kw[j][0] = pack_bf16(lv[2 * j].x, lv[2 * j].y);
      kw[j][1] = pack_bf16(lv[2 * j].z, lv[2 * j].w);
      kw[j][2] = pack_bf16(lv[2 * j + 1].x, lv[2 * j + 1].y);
      kw[j][3] = pack_bf16(lv[2 * j + 1].z, lv[2 * j + 1].w);
    }
    #pragma unroll
    for (int j = 0; j < 4; ++j) {
      const int key = kb * 8 + h * 4 + j;
      U16x8 t;
      t.w[0] = kw[j][0]; t.w[1] = kw[j][1]; t.w[2] = kw[j][2]; t.w[3] = kw[j][3];
      *(short8*)(xrow + key * 512 + ((dg ^ swzf(key)) * 8)) = t.v;
    }
    #pragma unroll
    for (int i = 0; i < 8; ++i) {
      const int ii = (i + dg) & 7;
      const int d  = dg * 8 + ii;
      const int p  = ii >> 1;
      uint2 u;
      if (ii & 1) {
        u.x = (kw[0][p] >> 16) | (kw[1][p] & 0xFFFF0000u);
        u.y = (kw[2][p] >> 16) | (kw[3][p] & 0xFFFF0000u);
      } else {
        u.x = (kw[0][p] & 0xFFFFu) | (kw[1][p] << 16);
        u.y = (kw[2][p] & 0xFFFFu) | (kw[3][p] << 16);
      }
      *(uint2*)(xcol + kb * 4096 + d * 8 + h * 4) = u;
    }
  };

  // ---- Q fragments (A-layout: A[m=l15][k=quad*8+j]), scale folded in ----
  short8 qf[16];
  {
    const float* qrow = Xb + (size_t)(q0 + wset * 16 + l15) * Dm + quad * 8;
    #pragma unroll
    for (int kk = 0; kk < 16; ++kk) {
      float4 a = *(const float4*)(qrow + kk * 32);
      float4 c = *(const float4*)(qrow + kk * 32 + 4);
      U16x8 t;
      t.w[0] = pack_bf16(a.x * SCALE, a.y * SCALE);
      t.w[1] = pack_bf16(a.z * SCALE, a.w * SCALE);
      t.w[2] = pack_bf16(c.x * SCALE, c.y * SCALE);
      t.w[3] = pack_bf16(c.z * SCALE, c.w * SCALE);
      qf[kk] = t.v;
    }
  }

  floatx4 o[4][4];  // o[qset][ngroup]: O[64 q][w*64 + n*16 + l15]
  #pragma unroll
  for (int s = 0; s < 4; ++s)
    #pragma unroll
    for (int n = 0; n < 4; ++n) o[s][n] = (floatx4){0.f, 0.f, 0.f, 0.f};
  floatx4 l_acc = (floatx4){0.f, 0.f, 0.f, 0.f};
  short8 onesf;
  { U16x8 t; t.w[0] = t.w[1] = t.w[2] = t.w[3] = 0x3F803F80u; onesf = t.v; }

  // ---- prologue: tile 0 into buf 0 ----
  if constexpr (PRE) {
    uint4 lv0[8];
    load_img(0, lv0);
    write_img(lv0, 0);
  } else {
    float4 lv0[8];
    load_tile(0, lv0);
    write_tile(lv0, 0);
  }
  __syncthreads();

  const int key0 = kh * 16;
  const int keyr = key0 + l15;
  const int swzr = swzf(keyr);

  for (int kt = 0; kt < 128; ++kt) {
    const int cur = kt & 1;
    const ushort* const xrow_r = SH + cur * 32768;
    const ushort* const xcol_r = xrow_r + 16384;

    // issue next tile's global loads early (register-destined, hidden by QK)
    uint4 li[8];
    float4 lf[8];
    if constexpr (PRE) load_img((kt + 1) & 127, li);
    else load_tile(((kt + 1) & 127) * 32, lf);

    // ---- QK^T: S[16 q][16 keys] (this wave's key half) ----
    floatx4 s = {0.f, 0.f, 0.f, 0.f};
    const ushort* const krow = xrow_r + keyr * 512;
    #pragma unroll
    for (int kk = 0; kk < 16; ++kk) {
      short8 kf = *(const short8*)(krow + (((kk * 4 + quad) ^ swzr) * 8));
      s = __builtin_amdgcn_mfma_f32_16x16x32_bf16(qf[kk], kf, s, 0, 0, 0);
    }

    // ---- fixed-offset softmax -> shared P ----
    #pragma unroll
    for (int r = 0; r < 4; ++r) {
      float p = __expf(s[r] - MOFF);
      Psh[(wset * 16 + quad * 4 + r) * 40 + key0 + l15] =
          (ushort)((__float_as_uint(p) + 0x8000u) >> 16);
    }
    __syncthreads();  // barrier A: P visible; prior-tile reads of buf cur^1 done

    // ---- PV: O[64 q][64 dims of wave]; V frags reused across 4 q-sets ----
    short8 vf[4];
    #pragma unroll
    for (int n = 0; n < 4; ++n)
      vf[n] = *(const short8*)(xcol_r + quad * 4096 + (w * 64 + n * 16 + l15) * 8);
    #pragma unroll
    for (int sQ = 0; sQ < 4; ++sQ) {
      short8 pf = *(const short8*)(Psh + (sQ * 16 + l15) * 40 + quad * 8);
      if (sQ == wset)  // wave-uniform
        l_acc = __builtin_amdgcn_mfma_f32_16x16x32_bf16(pf, onesf, l_acc, 0, 0, 0);
      #pragma unroll
      for (int n = 0; n < 4; ++n)
        o[sQ][n] = __builtin_amdgcn_mfma_f32_16x16x32_bf16(pf, vf[n], o[sQ][n], 0, 0, 0);
    }

    // ---- stage next tile into the other buffer ----
    if constexpr (PRE) write_img(li, cur ^ 1);
    else write_tile(lf, cur ^ 1);
    __syncthreads();  // barrier B: staging visible; cur reads done
  }

  // ---- share l across waves (per-row sums; identical in wave pairs) ----
  if (kh == 0 && l15 == 0) {
    #pragma unroll
    for (int r = 0; r < 4; ++r) l_sh[wset * 16 + quad * 4 + r] = l_acc[r];
  }
  __syncthreads();

  // ---- epilogue: O / l, write fp32 ----
  #pragma unroll
  for (int sQ = 0; sQ < 4; ++sQ) {
    float linv[4];
    #pragma unroll
    for (int r = 0; r < 4; ++r)
      linv[r] = __builtin_amdgcn_rcpf(l_sh[sQ * 16 + quad * 4 + r]);
    #pragma unroll
    for (int n = 0; n < 4; ++n) {
      float* obase = Out + (size_t)b * Nq * Dm +
                     (size_t)(q0 + sQ * 16 + quad * 4) * Dm + w * 64 + n * 16 + l15;
      #pragma unroll
      for (int r = 0; r < 4; ++r)
        obase[(size_t)r * Dm] = o[sQ][n][r] * linv[r];
    }
  }
}

extern "C" void kernel_launch(void* const* d_in, const int* in_sizes, int n_in,
                              void* d_out, int out_size, void* d_ws, size_t ws_size,
                              hipStream_t stream) {
  const float* X = (const float*)d_in[0];
  float* Out = (float*)d_out;
  const size_t need = (size_t)512 << 16;  // 512 tiles x 64 KB = 32 MB
  if (ws_size >= need) {
    prepack<<<dim3(512), dim3(256), 0, stream>>>(X, (ushort*)d_ws);
    attn_fused<true><<<dim3(256), dim3(512), 0, stream>>>(X, (const ushort*)d_ws, Out);
  } else {
    attn_fused<false><<<dim3(256), dim3(512), 0, stream>>>(X, nullptr, Out);
  }
}

// Round 7
// 657.620 us; speedup vs baseline: 1.1927x; 1.0051x over previous
//
#include <hip/hip_runtime.h>

// Fused attention, Q=K=V=X: out = softmax(X X^T / sqrt(512)) X
// B=4, N=4096, D=512, fp32 in/out, bf16 MFMA compute.
//
// Round-7: r6 passed but compiled at 108 VGPRs (no 2nd launch_bounds arg ->
// compiler default budget) and spilled ~950 MB of scratch per dispatch.
// Fix: __launch_bounds__(512, 1) -- 1 block/CU (forced by 136 KB LDS anyway)
// = 2 waves/SIMD = 256 VGPRs/wave, fits the ~200-reg working set. History:
// (512,2) -> 128 regs [r3, spilled]; unspecified -> 108 [r6, spilled].
// Structure (verified passing in r6): prepack kernel emits each 32-key tile
// as the exact 64 KB LDS image (swizzled row half | transposed col half);
// attention kernel stages it via registers (coalesced uint4 loads at loop
// top, linear ds_write_b128 at tail). 8 waves: q-set w&3, key-half w>>2;
// block-shared P[64][40]; PV splits dims (V frags reused by 4 q-sets);
// row-sum l via MFMA ones-operand; fixed-offset softmax exp(s-24).
// NOTE: global_load_lds DMA staging corrupted data here (r5 absmax 5.06,
// r6 bisect proves image was fine) -- do not reintroduce without a probe.

#define Nq 4096
#define Dm 512
#define SCALE 0.044194173824159216f  // 1/sqrt(512)
#define MOFF 24.0f                   // fixed softmax offset (max score ~29)

typedef __attribute__((ext_vector_type(8))) short short8;
typedef __attribute__((ext_vector_type(4))) float floatx4;

union U16x8 { short8 v; uint w[4]; };
union U16x8b { uint4 v; ushort u[8]; };

__device__ __forceinline__ uint pack_bf16(float a, float b) {
  // round-half-up bf16(a) in low 16, bf16(b) in high 16
  uint ua = __float_as_uint(a) + 0x8000u;
  uint ub = __float_as_uint(b) + 0x8000u;
  return (ua >> 16) | (ub & 0xFFFF0000u);
}

__device__ __forceinline__ int swzf(int key) {
  return (key & 7) ^ ((key >> 3) << 1);  // row-image block swizzle
}

// ---- prepack: X fp32 -> G[b][kt][64 KB tile image] (bf16) ------------------
// image ushort layout: [0,16384): row half  R[key*512 + jj*8 + e] =
//   X[key][(jj^swzf(key))*8+e];  [16384,32768): col half C[kb*4096 + d*8 + t]
//   = X[kb*8+t][d]
__global__ __launch_bounds__(256) void prepack(const float* __restrict__ X,
                                               ushort* __restrict__ G) {
  __shared__ __attribute__((aligned(16))) ushort R[16384];
  __shared__ __attribute__((aligned(16))) ushort C[16384];
  const int t  = threadIdx.x;
  const int b  = blockIdx.x >> 7;
  const int kt = blockIdx.x & 127;
  const float* src = X + ((size_t)b * Nq + kt * 32) * Dm;

  // phase 1: fp32 -> swizzled bf16 row-image in R (coalesced float4 loads)
  #pragma unroll
  for (int i = 0; i < 16; ++i) {
    int f = i * 256 + t;           // float4 index within the 32x512 tile
    int row = f >> 7, c = f & 127;
    float4 v = *(const float4*)(src + (size_t)row * Dm + c * 4);
    uint2 u;
    u.x = pack_bf16(v.x, v.y);
    u.y = pack_bf16(v.z, v.w);
    int jj = (c >> 1) ^ swzf(row);
    *(uint2*)(R + row * 512 + jj * 8 + (c & 1) * 4) = u;
  }
  __syncthreads();

  ushort* Gt = G + ((size_t)(b * 128 + kt) << 15);  // 32768 ush per tile
  // phase 2: R -> G row half (linear, coalesced)
  #pragma unroll
  for (int i = 0; i < 8; ++i) {
    int u = i * 256 + t;
    ((uint4*)Gt)[u] = ((const uint4*)R)[u];
  }
  // phase 3: build col-image in C (8x8 u16 register transpose per thread)
  {
    const int kb = t >> 6, dc = t & 63;
    U16x8b r[8];
    #pragma unroll
    for (int tt = 0; tt < 8; ++tt) {
      int key = kb * 8 + tt;
      r[tt].v = *(const uint4*)(R + key * 512 + (dc ^ swzf(key)) * 8);
    }
    #pragma unroll
    for (int i = 0; i < 8; ++i) {
      U16x8b o;
      #pragma unroll
      for (int tt = 0; tt < 8; ++tt) o.u[tt] = r[tt].u[i];
      *(uint4*)(C + kb * 4096 + (dc * 8 + i) * 8) = o.v;
    }
  }
  __syncthreads();
  // phase 4: C -> G col half (linear, coalesced)
  #pragma unroll
  for (int i = 0; i < 8; ++i) {
    int u = i * 256 + t;
    ((uint4*)(Gt + 16384))[u] = ((const uint4*)C)[u];
  }
}

// ---- fused attention kernel ------------------------------------------------
template <bool PRE>
__global__ __launch_bounds__(512, 1) void attn_fused(
    const float* __restrict__ X, const ushort* __restrict__ G,
    float* __restrict__ Out) {
  // ushort units: buf k at k*32768 (row 16384 | col 16384)
  // P at 65536: [64][40]; l_sh at 68096 (64 floats)
  __shared__ __attribute__((aligned(16))) ushort SH[68224];  // 136448 B
  ushort* const Psh = SH + 65536;
  float* const l_sh = (float*)(SH + 68096);

  const int tid  = threadIdx.x;
  const int w    = tid >> 6;
  const int lane = tid & 63;
  const int quad = lane >> 4;
  const int l15  = lane & 15;
  const int wset = w & 3;       // q-set (16 rows)
  const int kh   = w >> 2;      // key half of each 32-key tile
  const int b    = blockIdx.x & 3;
  const int qt   = blockIdx.x >> 2;
  const int q0   = qt * 64;
  const float* Xb = X + (size_t)b * Nq * Dm;
  const ushort* Gb = PRE ? (G + ((size_t)b << 22)) : (const ushort*)nullptr;

  // PRE staging: thread t owns 8 x 16B at linear offsets j*8192 + t*16
  auto load_img = [&](int kt_next, uint4* lv) {
    const uint4* Gt4 = (const uint4*)(Gb + ((size_t)kt_next << 15));
    #pragma unroll
    for (int j = 0; j < 8; ++j) lv[j] = Gt4[j * 512 + tid];
  };
  auto write_img = [&](const uint4* lv, int buf) {
    uint4* dst4 = (uint4*)(SH + buf * 32768);
    #pragma unroll
    for (int j = 0; j < 8; ++j) dst4[j * 512 + tid] = lv[j];
  };

  // fallback staging (no workspace): round-3 verified pack path
  const int kb = wset, h = kh, dg = lane;
  auto load_tile = [&](int k0, float4* lv) {
    const float* s = Xb + (size_t)(k0 + kb * 8 + h * 4) * Dm + dg * 8;
    #pragma unroll
    for (int j = 0; j < 4; ++j) {
      lv[2 * j]     = *(const float4*)(s + (size_t)j * Dm);
      lv[2 * j + 1] = *(const float4*)(s + (size_t)j * Dm + 4);
    }
  };
  auto write_tile = [&](const float4* lv, int buf) {
    ushort* const xrow = SH + buf * 32768;
    ushort* const xcol = xrow + 16384;
    uint kw[4][4];
    #pragma unroll
    for (int j = 0; j < 4; ++j) {
      kw[j][0] = pack_bf16(lv[2 * j].x, lv[2 * j].y);
      kw[j][1] = pack_bf16(lv[2 * j].z, lv[2 * j].w);
      kw[j][2] = pack_bf16(lv[2 * j + 1].x, lv[2 * j + 1].y);
      kw[j][3] = pack_bf16(lv[2 * j + 1].z, lv[2 * j + 1].w);
    }
    #pragma unroll
    for (int j = 0; j < 4; ++j) {
      const int key = kb * 8 + h * 4 + j;
      U16x8 t;
      t.w[0] = kw[j][0]; t.w[1] = kw[j][1]; t.w[2] = kw[j][2]; t.w[3] = kw[j][3];
      *(short8*)(xrow + key * 512 + ((dg ^ swzf(key)) * 8)) = t.v;
    }
    #pragma unroll
    for (int i = 0; i < 8; ++i) {
      const int ii = (i + dg) & 7;
      const int d  = dg * 8 + ii;
      const int p  = ii >> 1;
      uint2 u;
      if (ii & 1) {
        u.x = (kw[0][p] >> 16) | (kw[1][p] & 0xFFFF0000u);
        u.y = (kw[2][p] >> 16) | (kw[3][p] & 0xFFFF0000u);
      } else {
        u.x = (kw[0][p] & 0xFFFFu) | (kw[1][p] << 16);
        u.y = (kw[2][p] & 0xFFFFu) | (kw[3][p] << 16);
      }
      *(uint2*)(xcol + kb * 4096 + d * 8 + h * 4) = u;
    }
  };

  // ---- Q fragments (A-layout: A[m=l15][k=quad*8+j]), scale folded in ----
  short8 qf[16];
  {
    const float* qrow = Xb + (size_t)(q0 + wset * 16 + l15) * Dm + quad * 8;
    #pragma unroll
    for (int kk = 0; kk < 16; ++kk) {
      float4 a = *(const float4*)(qrow + kk * 32);
      float4 c = *(const float4*)(qrow + kk * 32 + 4);
      U16x8 t;
      t.w[0] = pack_bf16(a.x * SCALE, a.y * SCALE);
      t.w[1] = pack_bf16(a.z * SCALE, a.w * SCALE);
      t.w[2] = pack_bf16(c.x * SCALE, c.y * SCALE);
      t.w[3] = pack_bf16(c.z * SCALE, c.w * SCALE);
      qf[kk] = t.v;
    }
  }

  floatx4 o[4][4];  // o[qset][ngroup]: O[64 q][w*64 + n*16 + l15]
  #pragma unroll
  for (int s = 0; s < 4; ++s)
    #pragma unroll
    for (int n = 0; n < 4; ++n) o[s][n] = (floatx4){0.f, 0.f, 0.f, 0.f};
  floatx4 l_acc = (floatx4){0.f, 0.f, 0.f, 0.f};
  short8 onesf;
  { U16x8 t; t.w[0] = t.w[1] = t.w[2] = t.w[3] = 0x3F803F80u; onesf = t.v; }

  // ---- prologue: tile 0 into buf 0 ----
  if constexpr (PRE) {
    uint4 lv0[8];
    load_img(0, lv0);
    write_img(lv0, 0);
  } else {
    float4 lv0[8];
    load_tile(0, lv0);
    write_tile(lv0, 0);
  }
  __syncthreads();

  const int key0 = kh * 16;
  const int keyr = key0 + l15;
  const int swzr = swzf(keyr);

  for (int kt = 0; kt < 128; ++kt) {
    const int cur = kt & 1;
    const ushort* const xrow_r = SH + cur * 32768;
    const ushort* const xcol_r = xrow_r + 16384;

    // issue next tile's global loads early (register-destined, hidden by QK)
    uint4 li[8];
    float4 lf[8];
    if constexpr (PRE) load_img((kt + 1) & 127, li);
    else load_tile(((kt + 1) & 127) * 32, lf);

    // ---- QK^T: S[16 q][16 keys] (this wave's key half) ----
    floatx4 s = {0.f, 0.f, 0.f, 0.f};
    const ushort* const krow = xrow_r + keyr * 512;
    #pragma unroll
    for (int kk = 0; kk < 16; ++kk) {
      short8 kf = *(const short8*)(krow + (((kk * 4 + quad) ^ swzr) * 8));
      s = __builtin_amdgcn_mfma_f32_16x16x32_bf16(qf[kk], kf, s, 0, 0, 0);
    }

    // ---- fixed-offset softmax -> shared P ----
    #pragma unroll
    for (int r = 0; r < 4; ++r) {
      float p = __expf(s[r] - MOFF);
      Psh[(wset * 16 + quad * 4 + r) * 40 + key0 + l15] =
          (ushort)((__float_as_uint(p) + 0x8000u) >> 16);
    }
    __syncthreads();  // barrier A: P visible; prior-tile reads of buf cur^1 done

    // ---- PV: O[64 q][64 dims of wave]; V frags reused across 4 q-sets ----
    short8 vf[4];
    #pragma unroll
    for (int n = 0; n < 4; ++n)
      vf[n] = *(const short8*)(xcol_r + quad * 4096 + (w * 64 + n * 16 + l15) * 8);
    #pragma unroll
    for (int sQ = 0; sQ < 4; ++sQ) {
      short8 pf = *(const short8*)(Psh + (sQ * 16 + l15) * 40 + quad * 8);
      if (sQ == wset)  // wave-uniform
        l_acc = __builtin_amdgcn_mfma_f32_16x16x32_bf16(pf, onesf, l_acc, 0, 0, 0);
      #pragma unroll
      for (int n = 0; n < 4; ++n)
        o[sQ][n] = __builtin_amdgcn_mfma_f32_16x16x32_bf16(pf, vf[n], o[sQ][n], 0, 0, 0);
    }

    // ---- stage next tile into the other buffer ----
    if constexpr (PRE) write_img(li, cur ^ 1);
    else write_tile(lf, cur ^ 1);
    __syncthreads();  // barrier B: staging visible; cur reads done
  }

  // ---- share l across waves (per-row sums; identical in wave pairs) ----
  if (kh == 0 && l15 == 0) {
    #pragma unroll
    for (int r = 0; r < 4; ++r) l_sh[wset * 16 + quad * 4 + r] = l_acc[r];
  }
  __syncthreads();

  // ---- epilogue: O / l, write fp32 ----
  #pragma unroll
  for (int sQ = 0; sQ < 4; ++sQ) {
    float linv[4];
    #pragma unroll
    for (int r = 0; r < 4; ++r)
      linv[r] = __builtin_amdgcn_rcpf(l_sh[sQ * 16 + quad * 4 + r]);
    #pragma unroll
    for (int n = 0; n < 4; ++n) {
      float* obase = Out + (size_t)b * Nq * Dm +
                     (size_t)(q0 + sQ * 16 + quad * 4) * Dm + w * 64 + n * 16 + l15;
      #pragma unroll
      for (int r = 0; r < 4; ++r)
        obase[(size_t)r * Dm] = o[sQ][n][r] * linv[r];
    }
  }
}

extern "C" void kernel_launch(void* const* d_in, const int* in_sizes, int n_in,
                              void* d_out, int out_size, void* d_ws, size_t ws_size,
                              hipStream_t stream) {
  const float* X = (const float*)d_in[0];
  float* Out = (float*)d_out;
  const size_t need = (size_t)512 << 16;  // 512 tiles x 64 KB = 32 MB
  if (ws_size >= need) {
    prepack<<<dim3(512), dim3(256), 0, stream>>>(X, (ushort*)d_ws);
    attn_fused<true><<<dim3(256), dim3(512), 0, stream>>>(X, (const ushort*)d_ws, Out);
  } else {
    attn_fused<false><<<dim3(256), dim3(512), 0, stream>>>(X, nullptr, Out);
  }
}